// Round 18
// baseline (1394.594 us; speedup 1.0000x reference)
//
#include <hip/hip_runtime.h>
#include <math.h>

#define NN   10000
#define NE   80000
#define NG   64
#define HID  256
#define RBFK 16
#define NDEP 6
#define KA   16
#define KC   6
#define KE   5
#define DE   85
#define CATW 784

typedef __attribute__((ext_vector_type(8))) short bf16x8;
typedef __attribute__((ext_vector_type(4))) float f32x4;
typedef __attribute__((ext_vector_type(2))) __bf16 bf16v2;

#if __has_builtin(__builtin_amdgcn_fdot2_f32_bf16)
#define HAVE_BF16_DOT2 1
#else
#define HAVE_BF16_DOT2 0
#endif

static __device__ __forceinline__ float silu_f(float v) {
  return __fdividef(v, 1.0f + __expf(-v));
}

static __device__ __forceinline__ unsigned short f2bf(float f) {
  union { float f; unsigned int u; } v; v.f = f;
  unsigned int r = v.u + 0x7fff + ((v.u >> 16) & 1);
  return (unsigned short)(r >> 16);
}
static __device__ __forceinline__ float bf2f(unsigned short h) {
  union { unsigned int u; float f; } v; v.u = ((unsigned int)h) << 16;
  return v.f;
}
static __device__ __forceinline__ bf16v2 u2bf2(unsigned int u) {
  union { unsigned int u; bf16v2 v; } x; x.u = u; return x.v;
}

static __device__ __forceinline__ void gload16(const void* g, void* l) {
  __builtin_amdgcn_global_load_lds((const __attribute__((address_space(1))) unsigned int*)g,
                                   (__attribute__((address_space(3))) unsigned int*)l, 16, 0, 0);
}

// ---------------- weight transpose-converts ----------------
__global__ void convw_plain(const float* __restrict__ W, unsigned short* __restrict__ Wt, int K,
                            long long wt_dstride, int wt_rowoff) {
  __shared__ float T[32][65];
  int k0 = blockIdx.x * 32, n0 = blockIdx.y * 64, d = blockIdx.z;
  int tid = threadIdx.x;
  int nn = tid & 63, kr = tid >> 6;
  const float* Wd = W + (size_t)d * K * 256;
#pragma unroll
  for (int i = 0; i < 8; ++i) {
    int k = kr + i * 4;
    T[k][nn] = Wd[(size_t)(k0 + k) * 256 + n0 + nn];
  }
  __syncthreads();
  unsigned short* Wtd = Wt + (size_t)d * wt_dstride;
  int kk = tid & 31, nr = tid >> 5;
#pragma unroll
  for (int i = 0; i < 8; ++i) {
    int n = nr + i * 8;
    Wtd[(size_t)(wt_rowoff + n0 + n) * K + k0 + kk] = f2bf(T[kk][n]);
  }
}

__global__ void convw_nodeblk(const float* __restrict__ W, unsigned short* __restrict__ Wt,
                              int src_k0, int nt_base) {
  __shared__ float T[32][65];
  int k0 = blockIdx.x * 32, n0 = blockIdx.y * 64, d = blockIdx.z;
  int tid = threadIdx.x;
  int nn = tid & 63, kr = tid >> 6;
  const float* Wd = W + (size_t)d * CATW * 256;
#pragma unroll
  for (int i = 0; i < 8; ++i) {
    int k = kr + i * 4;
    T[k][nn] = Wd[(size_t)(src_k0 + k0 + k) * 256 + n0 + nn];
  }
  __syncthreads();
  unsigned short* Wtd = Wt + (size_t)d * 1024 * 256;
  int kk = tid & 31, nr = tid >> 5;
#pragma unroll
  for (int i = 0; i < 8; ++i) {
    int n = nr + i * 8;
    Wtd[(size_t)(nt_base + n0 + n) * 256 + k0 + kk] = f2bf(T[kk][n]);
  }
}

// wR [D][16][512] bf16
__global__ void convw_rbf(const float* __restrict__ phimW1, const float* __restrict__ psimW1,
                          unsigned short* __restrict__ wR) {
  int d = blockIdx.x, j = threadIdx.x;
  int jj = j & 255;
  const float* W = (j < 256) ? phimW1 : psimW1;
  for (int k = 0; k < 16; ++k)
    wR[((size_t)d * 16 + k) * 512 + j] = f2bf(W[(size_t)d * CATW * 256 + (size_t)(512 + k) * 256 + jj]);
}

// wRp [D][8][512] dwords
__global__ void convw_rbf2(const float* __restrict__ phimW1, const float* __restrict__ psimW1,
                           unsigned int* __restrict__ wRp) {
  int d = blockIdx.x, j = threadIdx.x;
  int jj = j & 255;
  const float* W = (j < 256) ? phimW1 : psimW1;
  const float* base = W + (size_t)d * CATW * 256;
  for (int p = 0; p < 8; ++p) {
    unsigned int lo = f2bf(base[(size_t)(512 + 2*p) * 256 + jj]);
    unsigned int hi = f2bf(base[(size_t)(512 + 2*p + 1) * 256 + jj]);
    wRp[((size_t)d * 8 + p) * 512 + j] = lo | (hi << 16);
  }
}

// ---------------- tables ----------------
__global__ void tables_kernel(const float* __restrict__ atom_W, const float* __restrict__ charge_W,
                              const float* __restrict__ bond_W, const float* __restrict__ fuse_W,
                              const float* __restrict__ fuse_b, const float* __restrict__ lift_W,
                              const float* __restrict__ lift_b,
                              float* __restrict__ tabA, float* __restrict__ tabC,
                              float* __restrict__ tabEf) {
  int r = blockIdx.x, k = threadIdx.x;
  if (r < KA) {
    float s = 0.f;
    for (int d = 0; d < DE; ++d) s += atom_W[r*DE + d] * fuse_W[d*HID + k];
    tabA[r*HID + k] = s + fuse_b[k];
  } else if (r < KA + KC) {
    int rr = r - KA;
    float s = 0.f;
    for (int d = 0; d < DE; ++d) s += charge_W[rr*DE + d] * fuse_W[(DE + d)*HID + k];
    tabC[rr*HID + k] = s;
  } else {
    int rr = r - KA - KC;
    float s = 0.f;
    for (int d = 0; d < DE; ++d) s += bond_W[rr*DE + d] * lift_W[d*HID + k];
    tabEf[rr*HID + k] = s + lift_b[k];
  }
}

// tabE1 [D][5][512] bf16
__global__ void tabe1_kernel(const float* __restrict__ tabEf,
                             const float* __restrict__ phimW1, const float* __restrict__ phimb1,
                             const float* __restrict__ psimW1, const float* __restrict__ psimb1,
                             unsigned short* __restrict__ tabE1) {
  int r = blockIdx.x, d = blockIdx.y, j = threadIdx.x;
  const float* W = (j < 256) ? phimW1 : psimW1;
  const float* b = (j < 256) ? phimb1 : psimb1;
  int jj = j & 255;
  float s = b[d*256 + jj];
  for (int k = 0; k < 256; ++k)
    s += tabEf[r*256 + k] * W[(size_t)d*CATW*256 + (size_t)(528 + k)*256 + jj];
  tabE1[((size_t)d*5 + r)*512 + j] = f2bf(s);
}

// ---------------- node / edge init ----------------
__global__ void node_init_kernel(const float* __restrict__ a_t, const float* __restrict__ c_t,
                                 const float* __restrict__ g_a, const float* __restrict__ g_c,
                                 const float* __restrict__ x_t, const float* __restrict__ tabA,
                                 const float* __restrict__ tabC, float* __restrict__ h,
                                 unsigned short* __restrict__ hbf, float* __restrict__ x) {
  int n = blockIdx.x;
  __shared__ int s_ia, s_ic;
  if (threadIdx.x == 0) {
    float best = -1e30f; int bi = 0;
    for (int j = 0; j < KA; ++j) {
      float v = logf(fmaxf(a_t[n*KA + j], 1e-12f)) + g_a[n*KA + j];
      if (v > best) { best = v; bi = j; }
    }
    s_ia = bi;
  }
  if (threadIdx.x == 1) {
    float best = -1e30f; int bi = 0;
    for (int j = 0; j < KC; ++j) {
      float v = logf(fmaxf(c_t[n*KC + j], 1e-12f)) + g_c[n*KC + j];
      if (v > best) { best = v; bi = j; }
    }
    s_ic = bi;
  }
  __syncthreads();
  int k = threadIdx.x;
  float v = tabA[s_ia*HID + k] + tabC[s_ic*HID + k];
  h[n*HID + k] = v;
  hbf[n*HID + k] = f2bf(v);
  if (k < 3) x[n*3 + k] = x_t[n*3 + k];
}

__global__ void edge_init_kernel(const float* __restrict__ e_t, const float* __restrict__ g_e,
                                 int* __restrict__ ie) {
  int e = blockIdx.x * blockDim.x + threadIdx.x;
  if (e >= NE) return;
  float best = -1e30f; int bi = 0;
  for (int j = 0; j < KE; ++j) {
    float v = logf(fmaxf(e_t[e*KE + j], 1e-12f)) + g_e[e*KE + j];
    if (v > best) { best = v; bi = j; }
  }
  ie[e] = bi;
}

// ---------------- CSR build ----------------
__global__ void hist_kernel(const int* __restrict__ dst, int* __restrict__ deg) {
  int e = blockIdx.x * 256 + threadIdx.x;
  if (e < NE) atomicAdd(&deg[dst[e]], 1);
}

__global__ void scan_kernel(const int* __restrict__ deg, int* __restrict__ rowstart,
                            int* __restrict__ cursor) {
  __shared__ int tmp[1024];
  int t = threadIdx.x;
  int base = t * 10;
  int local[10];
  int s = 0;
#pragma unroll
  for (int i = 0; i < 10; ++i) { local[i] = deg[base + i]; s += local[i]; }
  tmp[t] = s;
  __syncthreads();
  for (int off = 1; off < 1024; off <<= 1) {
    int v = (t >= off) ? tmp[t - off] : 0;
    __syncthreads();
    tmp[t] += v;
    __syncthreads();
  }
  int run = (t == 0) ? 0 : tmp[t - 1];
#pragma unroll
  for (int i = 0; i < 10; ++i) {
    rowstart[base + i] = run; cursor[base + i] = run; run += local[i];
  }
  if (t == 1023) rowstart[10240] = run;
}

__global__ void fill_kernel(const int* __restrict__ dst, int* __restrict__ cursor,
                            int* __restrict__ eids) {
  int e = blockIdx.x * 256 + threadIdx.x;
  if (e >= NE) return;
  int pos = atomicAdd(&cursor[dst[e]], 1);
  eids[pos] = e;
}

__global__ void sortrows_kernel(const int* __restrict__ rowstart, int* __restrict__ eids) {
  int n = blockIdx.x * 256 + threadIdx.x;
  if (n >= NN) return;
  int s = rowstart[n], e = rowstart[n + 1];
  for (int i = s + 1; i < e; ++i) {
    int v = eids[i]; int j = i - 1;
    while (j >= s && eids[j] > v) { eids[j + 1] = eids[j]; --j; }
    eids[j + 1] = v;
  }
}

// ---------------- graph boundaries ----------------
__global__ void gbound_kernel(const int* __restrict__ ng, int* __restrict__ gstart) {
  int n = blockIdx.x * 256 + threadIdx.x;
  if (n >= NN) return;
  if (n == 0) {
    for (int g = 0; g <= ng[0]; ++g) gstart[g] = 0;
  } else {
    int a = ng[n-1], b = ng[n];
    for (int g = a + 1; g <= b; ++g) gstart[g] = n;
  }
  if (n == NN - 1) {
    for (int g = ng[n] + 1; g <= NG; ++g) gstart[g] = NN;
  }
}

// ---------------- combine2 ----------------
__global__ __launch_bounds__(256) void combine2_kernel(
    const int* __restrict__ srcp, const int* __restrict__ dstp, const int* __restrict__ iep,
    const float* __restrict__ x,
    const unsigned short* __restrict__ P,
    const unsigned short* __restrict__ tabE1,
    const unsigned short* __restrict__ wR,
    const unsigned int* __restrict__ wRp,
    unsigned short* __restrict__ c1, unsigned short* __restrict__ ps1) {
  const int tid = threadIdx.x;
  const int lane = tid & 63;
  const int e = blockIdx.x * 4 + (tid >> 6);
  const int half = lane >> 5;
  const int c8 = (lane & 31) * 8;
  const int ds = dstp[e], sr = srcp[e], ib = iep[e];
  float r0 = x[ds*3+0] - x[sr*3+0];
  float r1 = x[ds*3+1] - x[sr*3+1];
  float r2 = x[ds*3+2] - x[sr*3+2];
  float dist = sqrtf(r0*r0 + r1*r1 + r2*r2);
  int klo = (int)(dist * 1.5f) - 3;
  klo = klo < 0 ? 0 : (klo > 8 ? 8 : klo);
  const unsigned short* Pb0 = P + (size_t)(half * 2) * NN * 256;
  const unsigned short* Pb1 = P + (size_t)(half * 2 + 1) * NN * 256;
  bf16x8 pa = *(const bf16x8*)&Pb0[(size_t)ds * 256 + c8];
  bf16x8 pb = *(const bf16x8*)&Pb1[(size_t)sr * 256 + c8];
  bf16x8 te = *(const bf16x8*)&tabE1[(size_t)ib * 512 + lane * 8];
  float zv[8];
#pragma unroll
  for (int j = 0; j < 8; ++j)
    zv[j] = bf2f((unsigned short)pa[j]) + bf2f((unsigned short)pb[j]) + bf2f((unsigned short)te[j]);
#if HAVE_BF16_DOT2
  int plo = klo >> 1;
  if (plo > 4) plo = 4;
#pragma unroll
  for (int pp = 0; pp < 4; ++pp) {
    int pr = plo + pp;
    float k0f = (float)(2 * pr);
    float z0 = (dist - 0.66666667f * k0f) * 1.6f;
    float z1 = (dist - 0.66666667f * (k0f + 1.0f)) * 1.6f;
    unsigned int rkp = (unsigned int)f2bf(__expf(-0.5f * z0 * z0)) |
                       ((unsigned int)f2bf(__expf(-0.5f * z1 * z1)) << 16);
    bf16v2 rv = u2bf2(rkp);
    const unsigned int* w8 = wRp + (size_t)pr * 512 + lane * 8;
    uint4 wa = *(const uint4*)w8;
    uint4 wb = *(const uint4*)(w8 + 4);
    zv[0] = __builtin_amdgcn_fdot2_f32_bf16(rv, u2bf2(wa.x), zv[0], false);
    zv[1] = __builtin_amdgcn_fdot2_f32_bf16(rv, u2bf2(wa.y), zv[1], false);
    zv[2] = __builtin_amdgcn_fdot2_f32_bf16(rv, u2bf2(wa.z), zv[2], false);
    zv[3] = __builtin_amdgcn_fdot2_f32_bf16(rv, u2bf2(wa.w), zv[3], false);
    zv[4] = __builtin_amdgcn_fdot2_f32_bf16(rv, u2bf2(wb.x), zv[4], false);
    zv[5] = __builtin_amdgcn_fdot2_f32_bf16(rv, u2bf2(wb.y), zv[5], false);
    zv[6] = __builtin_amdgcn_fdot2_f32_bf16(rv, u2bf2(wb.z), zv[6], false);
    zv[7] = __builtin_amdgcn_fdot2_f32_bf16(rv, u2bf2(wb.w), zv[7], false);
  }
#else
  (void)wRp;
#pragma unroll
  for (int kk = 0; kk < 8; ++kk) {
    int k = klo + kk;
    float z = (dist - 0.66666667f * (float)k) * 1.6f;
    float rk = __expf(-0.5f * z * z);
    bf16x8 wv = *(const bf16x8*)&wR[k * 512 + lane * 8];
#pragma unroll
    for (int j = 0; j < 8; ++j)
      zv[j] += rk * bf2f((unsigned short)wv[j]);
  }
#endif
  unsigned short ov[8];
#pragma unroll
  for (int j = 0; j < 8; ++j) ov[j] = f2bf(silu_f(zv[j]));
  unsigned short* outp = half ? ps1 : c1;
  *(uint4*)&outp[(size_t)e * 256 + c8] = *(uint4*)ov;
}

// ---------------- MFMA bf16 GEMM (proven structure) ----------------
template<int MODE, bool SILU, bool GATE, bool LNOUT, bool SMALL>
__global__ __launch_bounds__(SMALL ? 256 : 512, 4) void mfma_gemm(
    const unsigned short* __restrict__ A, const unsigned short* __restrict__ A2,
    const unsigned short* __restrict__ Wt,
    const float* __restrict__ bias, const float* __restrict__ bias2,
    unsigned short* __restrict__ C, unsigned short* __restrict__ C2,
    int M, int Kp, int Msplit,
    const float* __restrict__ gw2, float* __restrict__ gout,
    float* __restrict__ hf, unsigned short* __restrict__ hb,
    const float* __restrict__ lng, const float* __restrict__ lnb) {
  constexpr int BM = SMALL ? 64 : 128;
  constexpr int BQ = SMALL ? 8 : 4;
  __shared__ unsigned short lds[SMALL ? 20480 : 24576];
  unsigned short* As = lds;
  unsigned short* Bs = lds + BM * 64;
  const int tid = threadIdx.x;
  const int bn = blockIdx.x * 256;
  const int bm = blockIdx.y * BM;
  const int lane = tid & 63;
  const int w = tid >> 6;
  const int wr = SMALL ? 0 : (w >> 2);
  const int wc = SMALL ? w : (w & 3);
  const int subrow = lane >> 3;
  const int kd = 8 * ((lane & 7) ^ subrow);

  const bool half2 = (MODE == 4) && (bm >= Msplit);
  const unsigned short* Wb = Wt + (half2 ? 256 * 256 : 0);

  unsigned int offB[BQ];
#pragma unroll
  for (int q = 0; q < BQ; ++q)
    offB[q] = (unsigned)(bn + w * (BQ * 8) + q * 8 + subrow) * (unsigned)Kp;

  unsigned int offA[2];
#pragma unroll
  for (int q = 0; q < 2; ++q) {
    int m = bm + w * 16 + q * 8 + subrow;
    int mc = (m < M) ? m : (M - 1);
    offA[q] = (unsigned)mc * 256u;
  }

  const int nt = Kp >> 6;
  f32x4 acc[4][4] = {};

  for (int t = 0; t < nt; ++t) {
    const int k0 = t << 6;
#pragma unroll
    for (int q = 0; q < 2; ++q) {
      const unsigned short* gp;
      if (MODE == 2) gp = (k0 < 256) ? (A + offA[q] + k0 + kd) : (A2 + offA[q] + (k0 - 256) + kd);
      else gp = A + offA[q] + k0 + kd;
      gload16(gp, (char*)As + w * 2048 + q * 1024);
    }
#pragma unroll
    for (int q = 0; q < BQ; ++q)
      gload16(Wb + offB[q] + k0 + kd, (char*)Bs + w * (BQ * 1024) + q * 1024);
    __syncthreads();
#pragma unroll
    for (int ks = 0; ks < 2; ++ks) {
      const int kb = (ks * 64 + ((lane >> 4) << 4)) ^ ((lane & 7) << 4);
      bf16x8 bfv[4];
#pragma unroll
      for (int j = 0; j < 4; ++j)
        bfv[j] = *(const bf16x8*)((const char*)Bs + (wc * 64 + j * 16 + (lane & 15)) * 128 + kb);
#pragma unroll
      for (int i = 0; i < 4; ++i) {
        bf16x8 af = *(const bf16x8*)((const char*)As + (wr * 64 + i * 16 + (lane & 15)) * 128 + kb);
#pragma unroll
        for (int j = 0; j < 4; ++j)
          acc[i][j] = __builtin_amdgcn_mfma_f32_16x16x32_bf16(af, bfv[j], acc[i][j], 0, 0, 0);
      }
    }
    __syncthreads();
  }

  if (GATE) {
    float bcol[4], wcol[4];
#pragma unroll
    for (int j = 0; j < 4; ++j) {
      int col = wc * 64 + j * 16 + (lane & 15);
      bcol[j] = bias[col];
      wcol[j] = gw2[col];
    }
    float* part = (float*)lds;
#pragma unroll
    for (int i = 0; i < 4; ++i) {
#pragma unroll
      for (int q = 0; q < 4; ++q) {
        float lsum = 0.f;
#pragma unroll
        for (int j = 0; j < 4; ++j)
          lsum += silu_f(acc[i][j][q] + bcol[j]) * wcol[j];
        lsum += __shfl_xor(lsum, 1, 64);
        lsum += __shfl_xor(lsum, 2, 64);
        lsum += __shfl_xor(lsum, 4, 64);
        lsum += __shfl_xor(lsum, 8, 64);
        if ((lane & 15) == 0) {
          int rl = wr * 64 + i * 16 + ((lane >> 4) << 2) + q;
          part[wc * BM + rl] = lsum;
        }
      }
    }
    __syncthreads();
    if (tid < BM)
      gout[bm + tid] = part[tid] + part[BM + tid] + part[2*BM + tid] + part[3*BM + tid];
    return;
  }

  if (LNOUT) {
    float bcol[4], lgc[4], lbc[4];
#pragma unroll
    for (int j = 0; j < 4; ++j) {
      int col = wc * 64 + j * 16 + (lane & 15);
      bcol[j] = bias[col]; lgc[j] = lng[col]; lbc[j] = lnb[col];
    }
    float* part = (float*)lds;
    float* stat = part + 4 * BM;
#pragma unroll
    for (int i = 0; i < 4; ++i)
#pragma unroll
      for (int q = 0; q < 4; ++q) {
        int rl = wr * 64 + i * 16 + ((lane >> 4) << 2) + q;
        int grow = bm + rl;
        float s = 0.f;
#pragma unroll
        for (int j = 0; j < 4; ++j) {
          int col = wc * 64 + j * 16 + (lane & 15);
          float hv = (grow < M) ? hf[(size_t)grow * 256 + col] : 0.f;
          float zz = acc[i][j][q] + bcol[j] + hv;
          acc[i][j][q] = zz;
          s += zz;
        }
        s += __shfl_xor(s, 1, 64); s += __shfl_xor(s, 2, 64);
        s += __shfl_xor(s, 4, 64); s += __shfl_xor(s, 8, 64);
        if ((lane & 15) == 0) part[wc * BM + rl] = s;
      }
    __syncthreads();
    if (tid < BM)
      stat[tid] = (part[tid] + part[BM + tid] + part[2*BM + tid] + part[3*BM + tid]) * (1.f / 256.f);
    __syncthreads();
#pragma unroll
    for (int i = 0; i < 4; ++i)
#pragma unroll
      for (int q = 0; q < 4; ++q) {
        int rl = wr * 64 + i * 16 + ((lane >> 4) << 2) + q;
        float mu = stat[rl];
        float s2 = 0.f;
#pragma unroll
        for (int j = 0; j < 4; ++j) { float d_ = acc[i][j][q] - mu; s2 += d_ * d_; }
        s2 += __shfl_xor(s2, 1, 64); s2 += __shfl_xor(s2, 2, 64);
        s2 += __shfl_xor(s2, 4, 64); s2 += __shfl_xor(s2, 8, 64);
        if ((lane & 15) == 0) part[wc * BM + rl] = s2;
      }
    __syncthreads();
    if (tid < BM)
      stat[BM + tid] = 1.f / sqrtf((part[tid] + part[BM + tid] + part[2*BM + tid] + part[3*BM + tid]) * (1.f / 256.f) + 1e-5f);
    __syncthreads();
#pragma unroll
    for (int i = 0; i < 4; ++i)
#pragma unroll
      for (int q = 0; q < 4; ++q) {
        int rl = wr * 64 + i * 16 + ((lane >> 4) << 2) + q;
        int grow = bm + rl;
        if (grow < M) {
          float mu = stat[rl], rs = stat[BM + rl];
#pragma unroll
          for (int j = 0; j < 4; ++j) {
            int col = wc * 64 + j * 16 + (lane & 15);
            float o = (acc[i][j][q] - mu) * rs * lgc[j] + lbc[j];
            hf[(size_t)grow * 256 + col] = o;
            hb[(size_t)grow * 256 + col] = f2bf(o);
          }
        }
      }
    return;
  }

  // normal epilogue
  const float* biasw = bias;
  unsigned short* Cw = C;
  int rowoff = 0;
  if (MODE == 3) Cw = C + (size_t)(bn >> 8) * (size_t)M * 256;
  if (MODE == 4 && half2) { biasw = bias2; Cw = C2; rowoff = Msplit; }

  float bcol[4];
#pragma unroll
  for (int j = 0; j < 4; ++j) bcol[j] = biasw[wc * 64 + j * 16 + (lane & 15)];

  unsigned short* T = lds;
#pragma unroll
  for (int hh = 0; hh < 2; ++hh) {
    if ((wc >> 1) == hh) {
#pragma unroll
      for (int i = 0; i < 4; ++i)
#pragma unroll
        for (int j = 0; j < 4; ++j)
#pragma unroll
          for (int q = 0; q < 4; ++q) {
            int rl = wr * 64 + i * 16 + ((lane >> 4) << 2) + q;
            int cl = (wc & 1) * 64 + j * 16 + (lane & 15);
            float v = acc[i][j][q] + bcol[j];
            if (SILU) v = silu_f(v);
            T[rl * 136 + cl] = f2bf(v);
          }
    }
    __syncthreads();
#pragma unroll
    for (int it = 0; it < 4; ++it) {
      int row = it * (BM / 4) + (tid >> 4);
      int grow = bm + row;
      if (grow < M) {
        uint4 v = *(const uint4*)&T[row * 136 + (tid & 15) * 8];
        *(uint4*)&Cw[(size_t)(grow - rowoff) * 256 + hh * 128 + (tid & 15) * 8] = v;
      }
    }
    __syncthreads();
  }
}

// ---------------- fused m+gate: m = silu(c1@W2m+b2m) in LDS; gate = silu(m@Wx1+bx1)@wx2 ----------------
// 256 threads, BM=64. Same structure as upd_fused.
__global__ __launch_bounds__(256, 2) void mgate_kernel(
    const unsigned short* __restrict__ c1,
    const unsigned short* __restrict__ W2mt,  // [256][256] phimW2 transposed
    const unsigned short* __restrict__ Wx1t,  // [256][256] phixW1 transposed
    const float* __restrict__ b2m, const float* __restrict__ bx1,
    const float* __restrict__ wx2,
    float* __restrict__ gate, int M) {
  __shared__ unsigned short lds[16384 + 16896];   // Bs [256][64] | T [64][264]
  unsigned short* Bs = lds;
  unsigned short* As = lds + 16384;
  unsigned short* T  = lds + 16384;
  const int tid = threadIdx.x;
  const int bm = blockIdx.y * 64;
  const int lane = tid & 63;
  const int w = tid >> 6;
  const int subrow = lane >> 3;
  const int kd = 8 * ((lane & 7) ^ subrow);

  unsigned int offA[2];
#pragma unroll
  for (int q = 0; q < 2; ++q) {
    int m = bm + w * 16 + q * 8 + subrow;
    int mc = (m < M) ? m : (M - 1);
    offA[q] = (unsigned)mc * 256u;
  }
  unsigned int offB[8];
#pragma unroll
  for (int q = 0; q < 8; ++q)
    offB[q] = (unsigned)(w * 64 + q * 8 + subrow) * 256u;

  // ---- phase 1: acc = c1 @ W2m  (K=256) ----
  f32x4 acc[4][4] = {};
  for (int t = 0; t < 4; ++t) {
    const int k0 = t << 6;
#pragma unroll
    for (int q = 0; q < 2; ++q)
      gload16(c1 + offA[q] + k0 + kd, (char*)As + w * 2048 + q * 1024);
#pragma unroll
    for (int q = 0; q < 8; ++q)
      gload16(W2mt + offB[q] + k0 + kd, (char*)Bs + w * 8192 + q * 1024);
    __syncthreads();
#pragma unroll
    for (int ks = 0; ks < 2; ++ks) {
      const int kb = (ks * 64 + ((lane >> 4) << 4)) ^ ((lane & 7) << 4);
      bf16x8 bfv[4];
#pragma unroll
      for (int j = 0; j < 4; ++j)
        bfv[j] = *(const bf16x8*)((const char*)Bs + (w * 64 + j * 16 + (lane & 15)) * 128 + kb);
#pragma unroll
      for (int i = 0; i < 4; ++i) {
        bf16x8 af = *(const bf16x8*)((const char*)As + (i * 16 + (lane & 15)) * 128 + kb);
#pragma unroll
        for (int j = 0; j < 4; ++j)
          acc[i][j] = __builtin_amdgcn_mfma_f32_16x16x32_bf16(af, bfv[j], acc[i][j], 0, 0, 0);
      }
    }
    __syncthreads();
  }

  // ---- m -> T (bf16, silu) — identical rounding to old bufM path ----
  {
    float bcol[4];
#pragma unroll
    for (int j = 0; j < 4; ++j) bcol[j] = b2m[w * 64 + j * 16 + (lane & 15)];
#pragma unroll
    for (int i = 0; i < 4; ++i)
#pragma unroll
      for (int j = 0; j < 4; ++j)
#pragma unroll
        for (int q = 0; q < 4; ++q) {
          int rl = i * 16 + ((lane >> 4) << 2) + q;
          int cl = w * 64 + j * 16 + (lane & 15);
          T[rl * 264 + cl] = f2bf(silu_f(acc[i][j][q] + bcol[j]));
        }
  }
  __syncthreads();

  // ---- phase 2: acc2 = m @ Wx1  (K=256, A from T) ----
  f32x4 acc2[4][4] = {};
  for (int t = 0; t < 4; ++t) {
    const int k0 = t << 6;
#pragma unroll
    for (int q = 0; q < 8; ++q)
      gload16(Wx1t + offB[q] + k0 + kd, (char*)Bs + w * 8192 + q * 1024);
    __syncthreads();
#pragma unroll
    for (int ks = 0; ks < 2; ++ks) {
      const int kb = (ks * 64 + ((lane >> 4) << 4)) ^ ((lane & 7) << 4);
      const int ka = k0 + ks * 32 + ((lane >> 4) << 3);
      bf16x8 bfv[4];
#pragma unroll
      for (int j = 0; j < 4; ++j)
        bfv[j] = *(const bf16x8*)((const char*)Bs + (w * 64 + j * 16 + (lane & 15)) * 128 + kb);
#pragma unroll
      for (int i = 0; i < 4; ++i) {
        bf16x8 af = *(const bf16x8*)&T[(i * 16 + (lane & 15)) * 264 + ka];
#pragma unroll
        for (int j = 0; j < 4; ++j)
          acc2[i][j] = __builtin_amdgcn_mfma_f32_16x16x32_bf16(af, bfv[j], acc2[i][j], 0, 0, 0);
      }
    }
    __syncthreads();
  }

  // ---- gate reduce: gate[row] = sum_col silu(acc2+bx1) * wx2 ----
  {
    float bcol[4], wcol[4];
#pragma unroll
    for (int j = 0; j < 4; ++j) {
      int col = w * 64 + j * 16 + (lane & 15);
      bcol[j] = bx1[col];
      wcol[j] = wx2[col];
    }
    float* part = (float*)lds;   // overlaps Bs (dead)
#pragma unroll
    for (int i = 0; i < 4; ++i) {
#pragma unroll
      for (int q = 0; q < 4; ++q) {
        float lsum = 0.f;
#pragma unroll
        for (int j = 0; j < 4; ++j)
          lsum += silu_f(acc2[i][j][q] + bcol[j]) * wcol[j];
        lsum += __shfl_xor(lsum, 1, 64);
        lsum += __shfl_xor(lsum, 2, 64);
        lsum += __shfl_xor(lsum, 4, 64);
        lsum += __shfl_xor(lsum, 8, 64);
        if ((lane & 15) == 0) {
          int rl = i * 16 + ((lane >> 4) << 2) + q;
          part[w * 64 + rl] = lsum;
        }
      }
    }
    __syncthreads();
    if (tid < 64) {
      int grow = bm + tid;
      if (grow < M)
        gate[grow] = part[tid] + part[64 + tid] + part[128 + tid] + part[192 + tid];
    }
  }
}

// ---------------- fused node update (proven r17) ----------------
__global__ __launch_bounds__(256, 2) void upd_fused_kernel(
    const unsigned short* __restrict__ hbf, const unsigned short* __restrict__ pmbf,
    const unsigned short* __restrict__ W1t, const unsigned short* __restrict__ W2t,
    const float* __restrict__ b1, const float* __restrict__ b2,
    float* __restrict__ hf, unsigned short* __restrict__ hb,
    const float* __restrict__ lng, const float* __restrict__ lnb, int M) {
  __shared__ unsigned short lds[16384 + 16896];
  unsigned short* Bs = lds;
  unsigned short* As = lds + 16384;
  unsigned short* T  = lds + 16384;
  const int tid = threadIdx.x;
  const int bm = blockIdx.y * 64;
  const int lane = tid & 63;
  const int w = tid >> 6;
  const int subrow = lane >> 3;
  const int kd = 8 * ((lane & 7) ^ subrow);

  unsigned int offA[2];
#pragma unroll
  for (int q = 0; q < 2; ++q) {
    int m = bm + w * 16 + q * 8 + subrow;
    int mc = (m < M) ? m : (M - 1);
    offA[q] = (unsigned)mc * 256u;
  }
  unsigned int offB1[8];
#pragma unroll
  for (int q = 0; q < 8; ++q)
    offB1[q] = (unsigned)(w * 64 + q * 8 + subrow) * 512u;

  f32x4 acc[4][4] = {};
  for (int t = 0; t < 8; ++t) {
    const int k0 = t << 6;
#pragma unroll
    for (int q = 0; q < 2; ++q) {
      const unsigned short* gp = (k0 < 256) ? (hbf + offA[q] + k0 + kd)
                                            : (pmbf + offA[q] + (k0 - 256) + kd);
      gload16(gp, (char*)As + w * 2048 + q * 1024);
    }
#pragma unroll
    for (int q = 0; q < 8; ++q)
      gload16(W1t + offB1[q] + k0 + kd, (char*)Bs + w * 8192 + q * 1024);
    __syncthreads();
#pragma unroll
    for (int ks = 0; ks < 2; ++ks) {
      const int kb = (ks * 64 + ((lane >> 4) << 4)) ^ ((lane & 7) << 4);
      bf16x8 bfv[4];
#pragma unroll
      for (int j = 0; j < 4; ++j)
        bfv[j] = *(const bf16x8*)((const char*)Bs + (w * 64 + j * 16 + (lane & 15)) * 128 + kb);
#pragma unroll
      for (int i = 0; i < 4; ++i) {
        bf16x8 af = *(const bf16x8*)((const char*)As + (i * 16 + (lane & 15)) * 128 + kb);
#pragma unroll
        for (int j = 0; j < 4; ++j)
          acc[i][j] = __builtin_amdgcn_mfma_f32_16x16x32_bf16(af, bfv[j], acc[i][j], 0, 0, 0);
      }
    }
    __syncthreads();
  }

  {
    float bcol[4];
#pragma unroll
    for (int j = 0; j < 4; ++j) bcol[j] = b1[w * 64 + j * 16 + (lane & 15)];
#pragma unroll
    for (int i = 0; i < 4; ++i)
#pragma unroll
      for (int j = 0; j < 4; ++j)
#pragma unroll
        for (int q = 0; q < 4; ++q) {
          int rl = i * 16 + ((lane >> 4) << 2) + q;
          int cl = w * 64 + j * 16 + (lane & 15);
          T[rl * 264 + cl] = f2bf(silu_f(acc[i][j][q] + bcol[j]));
        }
  }
  __syncthreads();

  unsigned int offB2[8];
#pragma unroll
  for (int q = 0; q < 8; ++q)
    offB2[q] = (unsigned)(w * 64 + q * 8 + subrow) * 256u;

  f32x4 acc2[4][4] = {};
  for (int t = 0; t < 4; ++t) {
    const int k0 = t << 6;
#pragma unroll
    for (int q = 0; q < 8; ++q)
      gload16(W2t + offB2[q] + k0 + kd, (char*)Bs + w * 8192 + q * 1024);
    __syncthreads();
#pragma unroll
    for (int ks = 0; ks < 2; ++ks) {
      const int kb = (ks * 64 + ((lane >> 4) << 4)) ^ ((lane & 7) << 4);
      const int ka = k0 + ks * 32 + ((lane >> 4) << 3);
      bf16x8 bfv[4];
#pragma unroll
      for (int j = 0; j < 4; ++j)
        bfv[j] = *(const bf16x8*)((const char*)Bs + (w * 64 + j * 16 + (lane & 15)) * 128 + kb);
#pragma unroll
      for (int i = 0; i < 4; ++i) {
        bf16x8 af = *(const bf16x8*)&T[(i * 16 + (lane & 15)) * 264 + ka];
#pragma unroll
        for (int j = 0; j < 4; ++j)
          acc2[i][j] = __builtin_amdgcn_mfma_f32_16x16x32_bf16(af, bfv[j], acc2[i][j], 0, 0, 0);
      }
    }
    __syncthreads();
  }

  {
    float bcol[4], lgc[4], lbc[4];
#pragma unroll
    for (int j = 0; j < 4; ++j) {
      int col = w * 64 + j * 16 + (lane & 15);
      bcol[j] = b2[col]; lgc[j] = lng[col]; lbc[j] = lnb[col];
    }
    float* part = (float*)lds;
    float* stat = part + 256;
#pragma unroll
    for (int i = 0; i < 4; ++i)
#pragma unroll
      for (int q = 0; q < 4; ++q) {
        int rl = i * 16 + ((lane >> 4) << 2) + q;
        int grow = bm + rl;
        float s = 0.f;
#pragma unroll
        for (int j = 0; j < 4; ++j) {
          int col = w * 64 + j * 16 + (lane & 15);
          float hv = (grow < M) ? hf[(size_t)grow * 256 + col] : 0.f;
          float zz = acc2[i][j][q] + bcol[j] + hv;
          acc2[i][j][q] = zz;
          s += zz;
        }
        s += __shfl_xor(s, 1, 64); s += __shfl_xor(s, 2, 64);
        s += __shfl_xor(s, 4, 64); s += __shfl_xor(s, 8, 64);
        if ((lane & 15) == 0) part[w * 64 + rl] = s;
      }
    __syncthreads();
    if (tid < 64)
      stat[tid] = (part[tid] + part[64 + tid] + part[128 + tid] + part[192 + tid]) * (1.f / 256.f);
    __syncthreads();
#pragma unroll
    for (int i = 0; i < 4; ++i)
#pragma unroll
      for (int q = 0; q < 4; ++q) {
        int rl = i * 16 + ((lane >> 4) << 2) + q;
        float mu = stat[rl];
        float s2 = 0.f;
#pragma unroll
        for (int j = 0; j < 4; ++j) { float d_ = acc2[i][j][q] - mu; s2 += d_ * d_; }
        s2 += __shfl_xor(s2, 1, 64); s2 += __shfl_xor(s2, 2, 64);
        s2 += __shfl_xor(s2, 4, 64); s2 += __shfl_xor(s2, 8, 64);
        if ((lane & 15) == 0) part[w * 64 + rl] = s2;
      }
    __syncthreads();
    if (tid < 64)
      stat[64 + tid] = 1.f / sqrtf((part[tid] + part[64 + tid] + part[128 + tid] + part[192 + tid]) * (1.f / 256.f) + 1e-5f);
    __syncthreads();
#pragma unroll
    for (int i = 0; i < 4; ++i)
#pragma unroll
      for (int q = 0; q < 4; ++q) {
        int rl = i * 16 + ((lane >> 4) << 2) + q;
        int grow = bm + rl;
        if (grow < M) {
          float mu = stat[rl], rs = stat[64 + rl];
#pragma unroll
          for (int j = 0; j < 4; ++j) {
            int col = w * 64 + j * 16 + (lane & 15);
            float o = (acc2[i][j][q] - mu) * rs * lgc[j] + lbc[j];
            hf[(size_t)grow * 256 + col] = o;
            hb[(size_t)grow * 256 + col] = f2bf(o);
          }
        }
      }
  }
}

// ---------------- CSR gather ----------------
__global__ void gather_pm_dx(const unsigned short* __restrict__ pm, const float* __restrict__ gate,
                             const float* __restrict__ xcur, const int* __restrict__ srcp,
                             const int* __restrict__ rowstart, const int* __restrict__ eids,
                             const float* __restrict__ gb2,
                             unsigned short* __restrict__ pmbf, float* __restrict__ xnxt) {
  int n = blockIdx.x, k = threadIdx.x;
  int s = rowstart[n], e1 = rowstart[n + 1];
  float acc = 0.f, dx = 0.f;
  float b2 = gb2[0];
  float xn = (k < 3) ? xcur[n*3 + k] : 0.f;
  for (int t = s; t < e1; ++t) {
    int e = eids[t];
    acc += bf2f(pm[(size_t)e*HID + k]);
    if (k < 3) dx += (xn - xcur[srcp[e]*3 + k]) * (gate[e] + b2);
  }
  pmbf[(size_t)n*HID + k] = f2bf(acc);
  if (k < 3) xnxt[n*3 + k] = xn + dx;
}

// ---------------- fused readout ----------------
__global__ void readout_kernel(const float* __restrict__ h, const int* __restrict__ gstart,
                               const float* __restrict__ head_W, const float* __restrict__ head_b,
                               float* __restrict__ out) {
  int g = blockIdx.x, k = threadIdx.x;
  int s = gstart[g], e = gstart[g + 1];
  float acc = 0.f;
  for (int n = s; n < e; ++n) acc += h[(size_t)n * HID + k];
  float v = acc * head_W[k];
  __shared__ float red[4];
  int lane = k & 63, wv = k >> 6;
#pragma unroll
  for (int off = 32; off > 0; off >>= 1) v += __shfl_down(v, off, 64);
  if (lane == 0) red[wv] = v;
  __syncthreads();
  if (k == 0) {
    float dot = red[0] + red[1] + red[2] + red[3];
    float c = fmaxf((float)(e - s), 1.0f);
    float val = (dot / c + head_b[0]) * 0.5f;
    out[g] = __fdividef(1.0f, 1.0f + __expf(-val));
  }
}

extern "C" void kernel_launch(void* const* d_in, const int* in_sizes, int n_in,
                              void* d_out, int out_size, void* d_ws, size_t ws_size,
                              hipStream_t stream) {
  (void)in_sizes; (void)n_in; (void)out_size; (void)ws_size;
  const float* a_t      = (const float*)d_in[0];
  const float* c_t      = (const float*)d_in[1];
  const float* e_t      = (const float*)d_in[2];
  const float* x_t      = (const float*)d_in[3];
  const float* g_a      = (const float*)d_in[4];
  const float* g_c      = (const float*)d_in[5];
  const float* g_e      = (const float*)d_in[6];
  const float* atom_W   = (const float*)d_in[7];
  const float* charge_W = (const float*)d_in[8];
  const float* bond_W   = (const float*)d_in[9];
  const float* fuse_W   = (const float*)d_in[10];
  const float* fuse_b   = (const float*)d_in[11];
  const float* lift_W   = (const float*)d_in[12];
  const float* lift_b   = (const float*)d_in[13];
  const float* phim_W1  = (const float*)d_in[14];
  const float* phim_b1  = (const float*)d_in[15];
  const float* phim_W2  = (const float*)d_in[16];
  const float* phim_b2  = (const float*)d_in[17];
  const float* phix_W1  = (const float*)d_in[18];
  const float* phix_b1  = (const float*)d_in[19];
  const float* phix_W2  = (const float*)d_in[20];
  const float* phix_b2  = (const float*)d_in[21];
  const float* psim_W1  = (const float*)d_in[22];
  const float* psim_b1  = (const float*)d_in[23];
  const float* psim_W2  = (const float*)d_in[24];
  const float* psim_b2  = (const float*)d_in[25];
  const float* updh_W1  = (const float*)d_in[26];
  const float* updh_b1  = (const float*)d_in[27];
  const float* updh_W2  = (const float*)d_in[28];
  const float* updh_b2  = (const float*)d_in[29];
  const float* ln_g     = (const float*)d_in[30];
  const float* ln_b     = (const float*)d_in[31];
  const float* head_W   = (const float*)d_in[32];
  const float* head_b   = (const float*)d_in[33];
  const int*   src      = (const int*)d_in[34];
  const int*   dst      = (const int*)d_in[35];
  const int*   ngraph   = (const int*)d_in[36];
  float* out = (float*)d_out;

  char* p = (char*)d_ws;
  auto carve = [&](size_t bytes) -> char* {
    char* r = p; p += (bytes + 255) & ~(size_t)255; return r;
  };
  float*          h     = (float*)carve((size_t)NN*HID*4);
  unsigned short* hbf   = (unsigned short*)carve((size_t)NN*HID*2);
  float*          xposA = (float*)carve((size_t)NN*3*4);
  float*          xposB = (float*)carve((size_t)NN*3*4);
  int*            ie    = (int*)carve((size_t)NE*4);
  float*          tabA  = (float*)carve((size_t)KA*HID*4);
  float*          tabC  = (float*)carve((size_t)KC*HID*4);
  float*          tabEf = (float*)carve((size_t)KE*HID*4);
  float*          gate  = (float*)carve((size_t)NE*4);
  unsigned short* pmbf  = (unsigned short*)carve((size_t)NN*HID*2);
  float*          zbias = (float*)carve(256*4);
  unsigned short* buf01 = (unsigned short*)carve((size_t)2*NE*HID*2);
  unsigned short* bufPM = (unsigned short*)carve((size_t)NE*HID*2);
  unsigned short* P     = (unsigned short*)carve((size_t)4*NN*HID*2);
  int* deg      = (int*)carve(10240*4);
  int* cursor   = (int*)carve(10240*4);
  int* rowstart = (int*)carve(10241*4);
  int* eids     = (int*)carve((size_t)NE*4);
  int* gstart   = (int*)carve((NG+1)*4);
  unsigned short* wNode  = (unsigned short*)carve((size_t)NDEP*1024*256*2);
  unsigned short* wMPM   = (unsigned short*)carve((size_t)NDEP*512*256*2);
  unsigned short* wPhix1 = (unsigned short*)carve((size_t)NDEP*256*256*2);
  unsigned short* wUpd1  = (unsigned short*)carve((size_t)NDEP*256*512*2);
  unsigned short* wUpd2  = (unsigned short*)carve((size_t)NDEP*256*256*2);
  unsigned short* wRbf   = (unsigned short*)carve((size_t)NDEP*16*512*2);
  unsigned int*   wRbfP  = (unsigned int*)carve((size_t)NDEP*8*512*4);
  unsigned short* tabE1  = (unsigned short*)carve((size_t)NDEP*5*512*2);

  unsigned short* c1buf = buf01;
  unsigned short* psbuf = buf01 + (size_t)NE*HID;

  convw_nodeblk<<<dim3(8,4,NDEP), 256, 0, stream>>>(phim_W1, wNode, 0,   0);
  convw_nodeblk<<<dim3(8,4,NDEP), 256, 0, stream>>>(phim_W1, wNode, 256, 256);
  convw_nodeblk<<<dim3(8,4,NDEP), 256, 0, stream>>>(psim_W1, wNode, 0,   512);
  convw_nodeblk<<<dim3(8,4,NDEP), 256, 0, stream>>>(psim_W1, wNode, 256, 768);
  convw_plain<<<dim3(8,4,NDEP), 256, 0, stream>>>(phim_W2, wMPM, 256, 512*256, 0);
  convw_plain<<<dim3(8,4,NDEP), 256, 0, stream>>>(psim_W2, wMPM, 256, 512*256, 256);
  convw_plain<<<dim3(8,4,NDEP), 256, 0, stream>>>(phix_W1, wPhix1, 256, 256*256, 0);
  convw_plain<<<dim3(8,4,NDEP), 256, 0, stream>>>(updh_W2, wUpd2, 256, 256*256, 0);
  convw_plain<<<dim3(16,4,NDEP), 256, 0, stream>>>(updh_W1, wUpd1, 512, 256*512, 0);
  convw_rbf<<<NDEP, 512, 0, stream>>>(phim_W1, psim_W1, wRbf);
  convw_rbf2<<<NDEP, 512, 0, stream>>>(phim_W1, psim_W1, wRbfP);
  hipMemsetAsync(zbias, 0, 256*4, stream);

  tables_kernel<<<KA + KC + KE, 256, 0, stream>>>(atom_W, charge_W, bond_W, fuse_W, fuse_b,
                                                  lift_W, lift_b, tabA, tabC, tabEf);
  tabe1_kernel<<<dim3(5, NDEP), 512, 0, stream>>>(tabEf, phim_W1, phim_b1, psim_W1, psim_b1, tabE1);
  node_init_kernel<<<NN, 256, 0, stream>>>(a_t, c_t, g_a, g_c, x_t, tabA, tabC, h, hbf, xposA);
  edge_init_kernel<<<(NE + 255)/256, 256, 0, stream>>>(e_t, g_e, ie);

  hipMemsetAsync(deg, 0, 10240*4, stream);
  hist_kernel<<<(NE + 255)/256, 256, 0, stream>>>(dst, deg);
  scan_kernel<<<1, 1024, 0, stream>>>(deg, rowstart, cursor);
  fill_kernel<<<(NE + 255)/256, 256, 0, stream>>>(dst, cursor, eids);
  sortrows_kernel<<<(NN + 255)/256, 256, 0, stream>>>(rowstart, eids);
  gbound_kernel<<<(NN + 255)/256, 256, 0, stream>>>(ngraph, gstart);

  dim3 gridP(4, (NN + 63)/64);
  dim3 gridE(1, NE/128);
  dim3 gridMG(1, (NE + 63)/64);
  dim3 gridNU(1, (NN + 63)/64);

  float* xcur = xposA;
  float* xnxt = xposB;

  for (int d = 0; d < NDEP; ++d) {
    const float* pb2m = phim_b2 + (size_t)d*HID;
    const float* pxb1 = phix_b1 + (size_t)d*HID;
    const float* pxW2 = phix_W2 + (size_t)d*HID;
    const float* pxb2 = phix_b2 + (size_t)d;
    const float* psb2 = psim_b2 + (size_t)d*HID;
    const float* pub1 = updh_b1 + (size_t)d*HID;
    const float* pub2 = updh_b2 + (size_t)d*HID;

    // P = h @ [W1_phim_dst | W1_phim_src | W1_psim_dst | W1_psim_src]
    mfma_gemm<3, false, false, false, true><<<gridP, 256, 0, stream>>>(
        hbf, nullptr, wNode + (size_t)d*1024*256, zbias, nullptr, P, nullptr, NN, 256, 0,
        nullptr, nullptr, nullptr, nullptr, nullptr, nullptr);
    // c1, ps1
    combine2_kernel<<<NE/4, 256, 0, stream>>>(
        src, dst, ie, xcur, P, tabE1 + (size_t)d*5*512, wRbf + (size_t)d*16*512,
        wRbfP + (size_t)d*8*512, c1buf, psbuf);
    // pm = silu(ps1 @ psim_W2 + b2)
    mfma_gemm<0, true, false, false, false><<<gridE, 512, 0, stream>>>(
        psbuf, nullptr, wMPM + (size_t)d*512*256 + 256*256, psb2, nullptr, bufPM, nullptr, NE, 256, 0,
        nullptr, nullptr, nullptr, nullptr, nullptr, nullptr);
    // gate = silu(silu(c1@phimW2+b2)@phixW1+b1)@phixW2  (fused, m never materialized)
    mgate_kernel<<<gridMG, 256, 0, stream>>>(
        c1buf, wMPM + (size_t)d*512*256, wPhix1 + (size_t)d*256*256,
        pb2m, pxb1, pxW2, gate, NE);
    // pm_sum -> pmbf ; x update
    gather_pm_dx<<<NN, 256, 0, stream>>>(bufPM, gate, xcur, src, rowstart, eids, pxb2, pmbf, xnxt);
    // fused upd1 + upd2 + LN
    upd_fused_kernel<<<gridNU, 256, 0, stream>>>(
        hbf, pmbf, wUpd1 + (size_t)d*256*512, wUpd2 + (size_t)d*256*256,
        pub1, pub2, h, hbf, ln_g + (size_t)d*HID, ln_b + (size_t)d*HID, NN);

    float* tmp = xcur; xcur = xnxt; xnxt = tmp;
  }

  readout_kernel<<<NG, 256, 0, stream>>>(h, gstart, head_W, head_b, out);
}

// Round 19
// 1376.045 us; speedup vs baseline: 1.0135x; 1.0135x over previous
//
#include <hip/hip_runtime.h>
#include <math.h>

#define NN   10000
#define NE   80000
#define NG   64
#define HID  256
#define RBFK 16
#define NDEP 6
#define KA   16
#define KC   6
#define KE   5
#define DE   85
#define CATW 784

typedef __attribute__((ext_vector_type(8))) short bf16x8;
typedef __attribute__((ext_vector_type(4))) float f32x4;
typedef __attribute__((ext_vector_type(2))) __bf16 bf16v2;

#if __has_builtin(__builtin_amdgcn_fdot2_f32_bf16)
#define HAVE_BF16_DOT2 1
#else
#define HAVE_BF16_DOT2 0
#endif

static __device__ __forceinline__ float silu_f(float v) {
  return __fdividef(v, 1.0f + __expf(-v));
}

static __device__ __forceinline__ unsigned short f2bf(float f) {
  union { float f; unsigned int u; } v; v.f = f;
  unsigned int r = v.u + 0x7fff + ((v.u >> 16) & 1);
  return (unsigned short)(r >> 16);
}
static __device__ __forceinline__ float bf2f(unsigned short h) {
  union { unsigned int u; float f; } v; v.u = ((unsigned int)h) << 16;
  return v.f;
}
static __device__ __forceinline__ bf16v2 u2bf2(unsigned int u) {
  union { unsigned int u; bf16v2 v; } x; x.u = u; return x.v;
}

static __device__ __forceinline__ void gload16(const void* g, void* l) {
  __builtin_amdgcn_global_load_lds((const __attribute__((address_space(1))) unsigned int*)g,
                                   (__attribute__((address_space(3))) unsigned int*)l, 16, 0, 0);
}

// ---------------- weight transpose-converts ----------------
__global__ void convw_plain(const float* __restrict__ W, unsigned short* __restrict__ Wt, int K,
                            long long wt_dstride, int wt_rowoff) {
  __shared__ float T[32][65];
  int k0 = blockIdx.x * 32, n0 = blockIdx.y * 64, d = blockIdx.z;
  int tid = threadIdx.x;
  int nn = tid & 63, kr = tid >> 6;
  const float* Wd = W + (size_t)d * K * 256;
#pragma unroll
  for (int i = 0; i < 8; ++i) {
    int k = kr + i * 4;
    T[k][nn] = Wd[(size_t)(k0 + k) * 256 + n0 + nn];
  }
  __syncthreads();
  unsigned short* Wtd = Wt + (size_t)d * wt_dstride;
  int kk = tid & 31, nr = tid >> 5;
#pragma unroll
  for (int i = 0; i < 8; ++i) {
    int n = nr + i * 8;
    Wtd[(size_t)(wt_rowoff + n0 + n) * K + k0 + kk] = f2bf(T[kk][n]);
  }
}

__global__ void convw_nodeblk(const float* __restrict__ W, unsigned short* __restrict__ Wt,
                              int src_k0, int nt_base) {
  __shared__ float T[32][65];
  int k0 = blockIdx.x * 32, n0 = blockIdx.y * 64, d = blockIdx.z;
  int tid = threadIdx.x;
  int nn = tid & 63, kr = tid >> 6;
  const float* Wd = W + (size_t)d * CATW * 256;
#pragma unroll
  for (int i = 0; i < 8; ++i) {
    int k = kr + i * 4;
    T[k][nn] = Wd[(size_t)(src_k0 + k0 + k) * 256 + n0 + nn];
  }
  __syncthreads();
  unsigned short* Wtd = Wt + (size_t)d * 1024 * 256;
  int kk = tid & 31, nr = tid >> 5;
#pragma unroll
  for (int i = 0; i < 8; ++i) {
    int n = nr + i * 8;
    Wtd[(size_t)(nt_base + n0 + n) * 256 + k0 + kk] = f2bf(T[kk][n]);
  }
}

// wR [D][16][512] bf16
__global__ void convw_rbf(const float* __restrict__ phimW1, const float* __restrict__ psimW1,
                          unsigned short* __restrict__ wR) {
  int d = blockIdx.x, j = threadIdx.x;
  int jj = j & 255;
  const float* W = (j < 256) ? phimW1 : psimW1;
  for (int k = 0; k < 16; ++k)
    wR[((size_t)d * 16 + k) * 512 + j] = f2bf(W[(size_t)d * CATW * 256 + (size_t)(512 + k) * 256 + jj]);
}

// wRp [D][8][512] dwords
__global__ void convw_rbf2(const float* __restrict__ phimW1, const float* __restrict__ psimW1,
                           unsigned int* __restrict__ wRp) {
  int d = blockIdx.x, j = threadIdx.x;
  int jj = j & 255;
  const float* W = (j < 256) ? phimW1 : psimW1;
  const float* base = W + (size_t)d * CATW * 256;
  for (int p = 0; p < 8; ++p) {
    unsigned int lo = f2bf(base[(size_t)(512 + 2*p) * 256 + jj]);
    unsigned int hi = f2bf(base[(size_t)(512 + 2*p + 1) * 256 + jj]);
    wRp[((size_t)d * 8 + p) * 512 + j] = lo | (hi << 16);
  }
}

// ---------------- tables ----------------
__global__ void tables_kernel(const float* __restrict__ atom_W, const float* __restrict__ charge_W,
                              const float* __restrict__ bond_W, const float* __restrict__ fuse_W,
                              const float* __restrict__ fuse_b, const float* __restrict__ lift_W,
                              const float* __restrict__ lift_b,
                              float* __restrict__ tabA, float* __restrict__ tabC,
                              float* __restrict__ tabEf) {
  int r = blockIdx.x, k = threadIdx.x;
  if (r < KA) {
    float s = 0.f;
    for (int d = 0; d < DE; ++d) s += atom_W[r*DE + d] * fuse_W[d*HID + k];
    tabA[r*HID + k] = s + fuse_b[k];
  } else if (r < KA + KC) {
    int rr = r - KA;
    float s = 0.f;
    for (int d = 0; d < DE; ++d) s += charge_W[rr*DE + d] * fuse_W[(DE + d)*HID + k];
    tabC[rr*HID + k] = s;
  } else {
    int rr = r - KA - KC;
    float s = 0.f;
    for (int d = 0; d < DE; ++d) s += bond_W[rr*DE + d] * lift_W[d*HID + k];
    tabEf[rr*HID + k] = s + lift_b[k];
  }
}

// tabE1 [D][5][512] bf16
__global__ void tabe1_kernel(const float* __restrict__ tabEf,
                             const float* __restrict__ phimW1, const float* __restrict__ phimb1,
                             const float* __restrict__ psimW1, const float* __restrict__ psimb1,
                             unsigned short* __restrict__ tabE1) {
  int r = blockIdx.x, d = blockIdx.y, j = threadIdx.x;
  const float* W = (j < 256) ? phimW1 : psimW1;
  const float* b = (j < 256) ? phimb1 : psimb1;
  int jj = j & 255;
  float s = b[d*256 + jj];
  for (int k = 0; k < 256; ++k)
    s += tabEf[r*256 + k] * W[(size_t)d*CATW*256 + (size_t)(528 + k)*256 + jj];
  tabE1[((size_t)d*5 + r)*512 + j] = f2bf(s);
}

// ---------------- node / edge init ----------------
__global__ void node_init_kernel(const float* __restrict__ a_t, const float* __restrict__ c_t,
                                 const float* __restrict__ g_a, const float* __restrict__ g_c,
                                 const float* __restrict__ x_t, const float* __restrict__ tabA,
                                 const float* __restrict__ tabC, float* __restrict__ h,
                                 unsigned short* __restrict__ hbf, float* __restrict__ x) {
  int n = blockIdx.x;
  __shared__ int s_ia, s_ic;
  if (threadIdx.x == 0) {
    float best = -1e30f; int bi = 0;
    for (int j = 0; j < KA; ++j) {
      float v = logf(fmaxf(a_t[n*KA + j], 1e-12f)) + g_a[n*KA + j];
      if (v > best) { best = v; bi = j; }
    }
    s_ia = bi;
  }
  if (threadIdx.x == 1) {
    float best = -1e30f; int bi = 0;
    for (int j = 0; j < KC; ++j) {
      float v = logf(fmaxf(c_t[n*KC + j], 1e-12f)) + g_c[n*KC + j];
      if (v > best) { best = v; bi = j; }
    }
    s_ic = bi;
  }
  __syncthreads();
  int k = threadIdx.x;
  float v = tabA[s_ia*HID + k] + tabC[s_ic*HID + k];
  h[n*HID + k] = v;
  hbf[n*HID + k] = f2bf(v);
  if (k < 3) x[n*3 + k] = x_t[n*3 + k];
}

__global__ void edge_init_kernel(const float* __restrict__ e_t, const float* __restrict__ g_e,
                                 int* __restrict__ ie) {
  int e = blockIdx.x * blockDim.x + threadIdx.x;
  if (e >= NE) return;
  float best = -1e30f; int bi = 0;
  for (int j = 0; j < KE; ++j) {
    float v = logf(fmaxf(e_t[e*KE + j], 1e-12f)) + g_e[e*KE + j];
    if (v > best) { best = v; bi = j; }
  }
  ie[e] = bi;
}

// ---------------- CSR build ----------------
__global__ void hist_kernel(const int* __restrict__ dst, int* __restrict__ deg) {
  int e = blockIdx.x * 256 + threadIdx.x;
  if (e < NE) atomicAdd(&deg[dst[e]], 1);
}

__global__ void scan_kernel(const int* __restrict__ deg, int* __restrict__ rowstart,
                            int* __restrict__ cursor) {
  __shared__ int tmp[1024];
  int t = threadIdx.x;
  int base = t * 10;
  int local[10];
  int s = 0;
#pragma unroll
  for (int i = 0; i < 10; ++i) { local[i] = deg[base + i]; s += local[i]; }
  tmp[t] = s;
  __syncthreads();
  for (int off = 1; off < 1024; off <<= 1) {
    int v = (t >= off) ? tmp[t - off] : 0;
    __syncthreads();
    tmp[t] += v;
    __syncthreads();
  }
  int run = (t == 0) ? 0 : tmp[t - 1];
#pragma unroll
  for (int i = 0; i < 10; ++i) {
    rowstart[base + i] = run; cursor[base + i] = run; run += local[i];
  }
  if (t == 1023) rowstart[10240] = run;
}

__global__ void fill_kernel(const int* __restrict__ dst, int* __restrict__ cursor,
                            int* __restrict__ eids) {
  int e = blockIdx.x * 256 + threadIdx.x;
  if (e >= NE) return;
  int pos = atomicAdd(&cursor[dst[e]], 1);
  eids[pos] = e;
}

__global__ void sortrows_kernel(const int* __restrict__ rowstart, int* __restrict__ eids) {
  int n = blockIdx.x * 256 + threadIdx.x;
  if (n >= NN) return;
  int s = rowstart[n], e = rowstart[n + 1];
  for (int i = s + 1; i < e; ++i) {
    int v = eids[i]; int j = i - 1;
    while (j >= s && eids[j] > v) { eids[j + 1] = eids[j]; --j; }
    eids[j + 1] = v;
  }
}

// ---------------- graph boundaries ----------------
__global__ void gbound_kernel(const int* __restrict__ ng, int* __restrict__ gstart) {
  int n = blockIdx.x * 256 + threadIdx.x;
  if (n >= NN) return;
  if (n == 0) {
    for (int g = 0; g <= ng[0]; ++g) gstart[g] = 0;
  } else {
    int a = ng[n-1], b = ng[n];
    for (int g = a + 1; g <= b; ++g) gstart[g] = n;
  }
  if (n == NN - 1) {
    for (int g = ng[n] + 1; g <= NG; ++g) gstart[g] = NN;
  }
}

// ---------------- combine2 ----------------
__global__ __launch_bounds__(256) void combine2_kernel(
    const int* __restrict__ srcp, const int* __restrict__ dstp, const int* __restrict__ iep,
    const float* __restrict__ x,
    const unsigned short* __restrict__ P,
    const unsigned short* __restrict__ tabE1,
    const unsigned short* __restrict__ wR,
    const unsigned int* __restrict__ wRp,
    unsigned short* __restrict__ c1, unsigned short* __restrict__ ps1) {
  const int tid = threadIdx.x;
  const int lane = tid & 63;
  const int e = blockIdx.x * 4 + (tid >> 6);
  const int half = lane >> 5;
  const int c8 = (lane & 31) * 8;
  const int ds = dstp[e], sr = srcp[e], ib = iep[e];
  float r0 = x[ds*3+0] - x[sr*3+0];
  float r1 = x[ds*3+1] - x[sr*3+1];
  float r2 = x[ds*3+2] - x[sr*3+2];
  float dist = sqrtf(r0*r0 + r1*r1 + r2*r2);
  int klo = (int)(dist * 1.5f) - 3;
  klo = klo < 0 ? 0 : (klo > 8 ? 8 : klo);
  const unsigned short* Pb0 = P + (size_t)(half * 2) * NN * 256;
  const unsigned short* Pb1 = P + (size_t)(half * 2 + 1) * NN * 256;
  bf16x8 pa = *(const bf16x8*)&Pb0[(size_t)ds * 256 + c8];
  bf16x8 pb = *(const bf16x8*)&Pb1[(size_t)sr * 256 + c8];
  bf16x8 te = *(const bf16x8*)&tabE1[(size_t)ib * 512 + lane * 8];
  float zv[8];
#pragma unroll
  for (int j = 0; j < 8; ++j)
    zv[j] = bf2f((unsigned short)pa[j]) + bf2f((unsigned short)pb[j]) + bf2f((unsigned short)te[j]);
#if HAVE_BF16_DOT2
  int plo = klo >> 1;
  if (plo > 4) plo = 4;
#pragma unroll
  for (int pp = 0; pp < 4; ++pp) {
    int pr = plo + pp;
    float k0f = (float)(2 * pr);
    float z0 = (dist - 0.66666667f * k0f) * 1.6f;
    float z1 = (dist - 0.66666667f * (k0f + 1.0f)) * 1.6f;
    unsigned int rkp = (unsigned int)f2bf(__expf(-0.5f * z0 * z0)) |
                       ((unsigned int)f2bf(__expf(-0.5f * z1 * z1)) << 16);
    bf16v2 rv = u2bf2(rkp);
    const unsigned int* w8 = wRp + (size_t)pr * 512 + lane * 8;
    uint4 wa = *(const uint4*)w8;
    uint4 wb = *(const uint4*)(w8 + 4);
    zv[0] = __builtin_amdgcn_fdot2_f32_bf16(rv, u2bf2(wa.x), zv[0], false);
    zv[1] = __builtin_amdgcn_fdot2_f32_bf16(rv, u2bf2(wa.y), zv[1], false);
    zv[2] = __builtin_amdgcn_fdot2_f32_bf16(rv, u2bf2(wa.z), zv[2], false);
    zv[3] = __builtin_amdgcn_fdot2_f32_bf16(rv, u2bf2(wa.w), zv[3], false);
    zv[4] = __builtin_amdgcn_fdot2_f32_bf16(rv, u2bf2(wb.x), zv[4], false);
    zv[5] = __builtin_amdgcn_fdot2_f32_bf16(rv, u2bf2(wb.y), zv[5], false);
    zv[6] = __builtin_amdgcn_fdot2_f32_bf16(rv, u2bf2(wb.z), zv[6], false);
    zv[7] = __builtin_amdgcn_fdot2_f32_bf16(rv, u2bf2(wb.w), zv[7], false);
  }
#else
  (void)wRp;
#pragma unroll
  for (int kk = 0; kk < 8; ++kk) {
    int k = klo + kk;
    float z = (dist - 0.66666667f * (float)k) * 1.6f;
    float rk = __expf(-0.5f * z * z);
    bf16x8 wv = *(const bf16x8*)&wR[k * 512 + lane * 8];
#pragma unroll
    for (int j = 0; j < 8; ++j)
      zv[j] += rk * bf2f((unsigned short)wv[j]);
  }
#endif
  unsigned short ov[8];
#pragma unroll
  for (int j = 0; j < 8; ++j) ov[j] = f2bf(silu_f(zv[j]));
  unsigned short* outp = half ? ps1 : c1;
  *(uint4*)&outp[(size_t)e * 256 + c8] = *(uint4*)ov;
}

// ---------------- MFMA bf16 GEMM (proven structure) ----------------
template<int MODE, bool SILU, bool GATE, bool LNOUT, bool SMALL>
__global__ __launch_bounds__(SMALL ? 256 : 512, 4) void mfma_gemm(
    const unsigned short* __restrict__ A, const unsigned short* __restrict__ A2,
    const unsigned short* __restrict__ Wt,
    const float* __restrict__ bias, const float* __restrict__ bias2,
    unsigned short* __restrict__ C, unsigned short* __restrict__ C2,
    int M, int Kp, int Msplit,
    const float* __restrict__ gw2, float* __restrict__ gout,
    float* __restrict__ hf, unsigned short* __restrict__ hb,
    const float* __restrict__ lng, const float* __restrict__ lnb) {
  constexpr int BM = SMALL ? 64 : 128;
  constexpr int BQ = SMALL ? 8 : 4;
  __shared__ unsigned short lds[SMALL ? 20480 : 24576];
  unsigned short* As = lds;
  unsigned short* Bs = lds + BM * 64;
  const int tid = threadIdx.x;
  const int bn = blockIdx.x * 256;
  const int bm = blockIdx.y * BM;
  const int lane = tid & 63;
  const int w = tid >> 6;
  const int wr = SMALL ? 0 : (w >> 2);
  const int wc = SMALL ? w : (w & 3);
  const int subrow = lane >> 3;
  const int kd = 8 * ((lane & 7) ^ subrow);

  const bool half2 = (MODE == 4) && (bm >= Msplit);
  const unsigned short* Wb = Wt + (half2 ? 256 * 256 : 0);

  unsigned int offB[BQ];
#pragma unroll
  for (int q = 0; q < BQ; ++q)
    offB[q] = (unsigned)(bn + w * (BQ * 8) + q * 8 + subrow) * (unsigned)Kp;

  unsigned int offA[2];
#pragma unroll
  for (int q = 0; q < 2; ++q) {
    int m = bm + w * 16 + q * 8 + subrow;
    int mc = (m < M) ? m : (M - 1);
    offA[q] = (unsigned)mc * 256u;
  }

  const int nt = Kp >> 6;
  f32x4 acc[4][4] = {};

  for (int t = 0; t < nt; ++t) {
    const int k0 = t << 6;
#pragma unroll
    for (int q = 0; q < 2; ++q) {
      const unsigned short* gp;
      if (MODE == 2) gp = (k0 < 256) ? (A + offA[q] + k0 + kd) : (A2 + offA[q] + (k0 - 256) + kd);
      else gp = A + offA[q] + k0 + kd;
      gload16(gp, (char*)As + w * 2048 + q * 1024);
    }
#pragma unroll
    for (int q = 0; q < BQ; ++q)
      gload16(Wb + offB[q] + k0 + kd, (char*)Bs + w * (BQ * 1024) + q * 1024);
    __syncthreads();
#pragma unroll
    for (int ks = 0; ks < 2; ++ks) {
      const int kb = (ks * 64 + ((lane >> 4) << 4)) ^ ((lane & 7) << 4);
      bf16x8 bfv[4];
#pragma unroll
      for (int j = 0; j < 4; ++j)
        bfv[j] = *(const bf16x8*)((const char*)Bs + (wc * 64 + j * 16 + (lane & 15)) * 128 + kb);
#pragma unroll
      for (int i = 0; i < 4; ++i) {
        bf16x8 af = *(const bf16x8*)((const char*)As + (wr * 64 + i * 16 + (lane & 15)) * 128 + kb);
#pragma unroll
        for (int j = 0; j < 4; ++j)
          acc[i][j] = __builtin_amdgcn_mfma_f32_16x16x32_bf16(af, bfv[j], acc[i][j], 0, 0, 0);
      }
    }
    __syncthreads();
  }

  if (GATE) {
    float bcol[4], wcol[4];
#pragma unroll
    for (int j = 0; j < 4; ++j) {
      int col = wc * 64 + j * 16 + (lane & 15);
      bcol[j] = bias[col];
      wcol[j] = gw2[col];
    }
    float* part = (float*)lds;
#pragma unroll
    for (int i = 0; i < 4; ++i) {
#pragma unroll
      for (int q = 0; q < 4; ++q) {
        float lsum = 0.f;
#pragma unroll
        for (int j = 0; j < 4; ++j)
          lsum += silu_f(acc[i][j][q] + bcol[j]) * wcol[j];
        lsum += __shfl_xor(lsum, 1, 64);
        lsum += __shfl_xor(lsum, 2, 64);
        lsum += __shfl_xor(lsum, 4, 64);
        lsum += __shfl_xor(lsum, 8, 64);
        if ((lane & 15) == 0) {
          int rl = wr * 64 + i * 16 + ((lane >> 4) << 2) + q;
          part[wc * BM + rl] = lsum;
        }
      }
    }
    __syncthreads();
    if (tid < BM)
      gout[bm + tid] = part[tid] + part[BM + tid] + part[2*BM + tid] + part[3*BM + tid];
    return;
  }

  if (LNOUT) {
    float bcol[4], lgc[4], lbc[4];
#pragma unroll
    for (int j = 0; j < 4; ++j) {
      int col = wc * 64 + j * 16 + (lane & 15);
      bcol[j] = bias[col]; lgc[j] = lng[col]; lbc[j] = lnb[col];
    }
    float* part = (float*)lds;
    float* stat = part + 4 * BM;
#pragma unroll
    for (int i = 0; i < 4; ++i)
#pragma unroll
      for (int q = 0; q < 4; ++q) {
        int rl = wr * 64 + i * 16 + ((lane >> 4) << 2) + q;
        int grow = bm + rl;
        float s = 0.f;
#pragma unroll
        for (int j = 0; j < 4; ++j) {
          int col = wc * 64 + j * 16 + (lane & 15);
          float hv = (grow < M) ? hf[(size_t)grow * 256 + col] : 0.f;
          float zz = acc[i][j][q] + bcol[j] + hv;
          acc[i][j][q] = zz;
          s += zz;
        }
        s += __shfl_xor(s, 1, 64); s += __shfl_xor(s, 2, 64);
        s += __shfl_xor(s, 4, 64); s += __shfl_xor(s, 8, 64);
        if ((lane & 15) == 0) part[wc * BM + rl] = s;
      }
    __syncthreads();
    if (tid < BM)
      stat[tid] = (part[tid] + part[BM + tid] + part[2*BM + tid] + part[3*BM + tid]) * (1.f / 256.f);
    __syncthreads();
#pragma unroll
    for (int i = 0; i < 4; ++i)
#pragma unroll
      for (int q = 0; q < 4; ++q) {
        int rl = wr * 64 + i * 16 + ((lane >> 4) << 2) + q;
        float mu = stat[rl];
        float s2 = 0.f;
#pragma unroll
        for (int j = 0; j < 4; ++j) { float d_ = acc[i][j][q] - mu; s2 += d_ * d_; }
        s2 += __shfl_xor(s2, 1, 64); s2 += __shfl_xor(s2, 2, 64);
        s2 += __shfl_xor(s2, 4, 64); s2 += __shfl_xor(s2, 8, 64);
        if ((lane & 15) == 0) part[wc * BM + rl] = s2;
      }
    __syncthreads();
    if (tid < BM)
      stat[BM + tid] = 1.f / sqrtf((part[tid] + part[BM + tid] + part[2*BM + tid] + part[3*BM + tid]) * (1.f / 256.f) + 1e-5f);
    __syncthreads();
#pragma unroll
    for (int i = 0; i < 4; ++i)
#pragma unroll
      for (int q = 0; q < 4; ++q) {
        int rl = wr * 64 + i * 16 + ((lane >> 4) << 2) + q;
        int grow = bm + rl;
        if (grow < M) {
          float mu = stat[rl], rs = stat[BM + rl];
#pragma unroll
          for (int j = 0; j < 4; ++j) {
            int col = wc * 64 + j * 16 + (lane & 15);
            float o = (acc[i][j][q] - mu) * rs * lgc[j] + lbc[j];
            hf[(size_t)grow * 256 + col] = o;
            hb[(size_t)grow * 256 + col] = f2bf(o);
          }
        }
      }
    return;
  }

  // normal epilogue
  const float* biasw = bias;
  unsigned short* Cw = C;
  int rowoff = 0;
  if (MODE == 3) Cw = C + (size_t)(bn >> 8) * (size_t)M * 256;
  if (MODE == 4 && half2) { biasw = bias2; Cw = C2; rowoff = Msplit; }

  float bcol[4];
#pragma unroll
  for (int j = 0; j < 4; ++j) bcol[j] = biasw[wc * 64 + j * 16 + (lane & 15)];

  unsigned short* T = lds;
#pragma unroll
  for (int hh = 0; hh < 2; ++hh) {
    if ((wc >> 1) == hh) {
#pragma unroll
      for (int i = 0; i < 4; ++i)
#pragma unroll
        for (int j = 0; j < 4; ++j)
#pragma unroll
          for (int q = 0; q < 4; ++q) {
            int rl = wr * 64 + i * 16 + ((lane >> 4) << 2) + q;
            int cl = (wc & 1) * 64 + j * 16 + (lane & 15);
            float v = acc[i][j][q] + bcol[j];
            if (SILU) v = silu_f(v);
            T[rl * 136 + cl] = f2bf(v);
          }
    }
    __syncthreads();
#pragma unroll
    for (int it = 0; it < 4; ++it) {
      int row = it * (BM / 4) + (tid >> 4);
      int grow = bm + row;
      if (grow < M) {
        uint4 v = *(const uint4*)&T[row * 136 + (tid & 15) * 8];
        *(uint4*)&Cw[(size_t)(grow - rowoff) * 256 + hh * 128 + (tid & 15) * 8] = v;
      }
    }
    __syncthreads();
  }
}

// ---------------- fused node update (proven r17) ----------------
__global__ __launch_bounds__(256, 2) void upd_fused_kernel(
    const unsigned short* __restrict__ hbf, const unsigned short* __restrict__ pmbf,
    const unsigned short* __restrict__ W1t, const unsigned short* __restrict__ W2t,
    const float* __restrict__ b1, const float* __restrict__ b2,
    float* __restrict__ hf, unsigned short* __restrict__ hb,
    const float* __restrict__ lng, const float* __restrict__ lnb, int M) {
  __shared__ unsigned short lds[16384 + 16896];
  unsigned short* Bs = lds;
  unsigned short* As = lds + 16384;
  unsigned short* T  = lds + 16384;
  const int tid = threadIdx.x;
  const int bm = blockIdx.y * 64;
  const int lane = tid & 63;
  const int w = tid >> 6;
  const int subrow = lane >> 3;
  const int kd = 8 * ((lane & 7) ^ subrow);

  unsigned int offA[2];
#pragma unroll
  for (int q = 0; q < 2; ++q) {
    int m = bm + w * 16 + q * 8 + subrow;
    int mc = (m < M) ? m : (M - 1);
    offA[q] = (unsigned)mc * 256u;
  }
  unsigned int offB1[8];
#pragma unroll
  for (int q = 0; q < 8; ++q)
    offB1[q] = (unsigned)(w * 64 + q * 8 + subrow) * 512u;

  f32x4 acc[4][4] = {};
  for (int t = 0; t < 8; ++t) {
    const int k0 = t << 6;
#pragma unroll
    for (int q = 0; q < 2; ++q) {
      const unsigned short* gp = (k0 < 256) ? (hbf + offA[q] + k0 + kd)
                                            : (pmbf + offA[q] + (k0 - 256) + kd);
      gload16(gp, (char*)As + w * 2048 + q * 1024);
    }
#pragma unroll
    for (int q = 0; q < 8; ++q)
      gload16(W1t + offB1[q] + k0 + kd, (char*)Bs + w * 8192 + q * 1024);
    __syncthreads();
#pragma unroll
    for (int ks = 0; ks < 2; ++ks) {
      const int kb = (ks * 64 + ((lane >> 4) << 4)) ^ ((lane & 7) << 4);
      bf16x8 bfv[4];
#pragma unroll
      for (int j = 0; j < 4; ++j)
        bfv[j] = *(const bf16x8*)((const char*)Bs + (w * 64 + j * 16 + (lane & 15)) * 128 + kb);
#pragma unroll
      for (int i = 0; i < 4; ++i) {
        bf16x8 af = *(const bf16x8*)((const char*)As + (i * 16 + (lane & 15)) * 128 + kb);
#pragma unroll
        for (int j = 0; j < 4; ++j)
          acc[i][j] = __builtin_amdgcn_mfma_f32_16x16x32_bf16(af, bfv[j], acc[i][j], 0, 0, 0);
      }
    }
    __syncthreads();
  }

  {
    float bcol[4];
#pragma unroll
    for (int j = 0; j < 4; ++j) bcol[j] = b1[w * 64 + j * 16 + (lane & 15)];
#pragma unroll
    for (int i = 0; i < 4; ++i)
#pragma unroll
      for (int j = 0; j < 4; ++j)
#pragma unroll
        for (int q = 0; q < 4; ++q) {
          int rl = i * 16 + ((lane >> 4) << 2) + q;
          int cl = w * 64 + j * 16 + (lane & 15);
          T[rl * 264 + cl] = f2bf(silu_f(acc[i][j][q] + bcol[j]));
        }
  }
  __syncthreads();

  unsigned int offB2[8];
#pragma unroll
  for (int q = 0; q < 8; ++q)
    offB2[q] = (unsigned)(w * 64 + q * 8 + subrow) * 256u;

  f32x4 acc2[4][4] = {};
  for (int t = 0; t < 4; ++t) {
    const int k0 = t << 6;
#pragma unroll
    for (int q = 0; q < 8; ++q)
      gload16(W2t + offB2[q] + k0 + kd, (char*)Bs + w * 8192 + q * 1024);
    __syncthreads();
#pragma unroll
    for (int ks = 0; ks < 2; ++ks) {
      const int kb = (ks * 64 + ((lane >> 4) << 4)) ^ ((lane & 7) << 4);
      const int ka = k0 + ks * 32 + ((lane >> 4) << 3);
      bf16x8 bfv[4];
#pragma unroll
      for (int j = 0; j < 4; ++j)
        bfv[j] = *(const bf16x8*)((const char*)Bs + (w * 64 + j * 16 + (lane & 15)) * 128 + kb);
#pragma unroll
      for (int i = 0; i < 4; ++i) {
        bf16x8 af = *(const bf16x8*)&T[(i * 16 + (lane & 15)) * 264 + ka];
#pragma unroll
        for (int j = 0; j < 4; ++j)
          acc2[i][j] = __builtin_amdgcn_mfma_f32_16x16x32_bf16(af, bfv[j], acc2[i][j], 0, 0, 0);
      }
    }
    __syncthreads();
  }

  {
    float bcol[4], lgc[4], lbc[4];
#pragma unroll
    for (int j = 0; j < 4; ++j) {
      int col = w * 64 + j * 16 + (lane & 15);
      bcol[j] = b2[col]; lgc[j] = lng[col]; lbc[j] = lnb[col];
    }
    float* part = (float*)lds;
    float* stat = part + 256;
#pragma unroll
    for (int i = 0; i < 4; ++i)
#pragma unroll
      for (int q = 0; q < 4; ++q) {
        int rl = i * 16 + ((lane >> 4) << 2) + q;
        int grow = bm + rl;
        float s = 0.f;
#pragma unroll
        for (int j = 0; j < 4; ++j) {
          int col = w * 64 + j * 16 + (lane & 15);
          float hv = (grow < M) ? hf[(size_t)grow * 256 + col] : 0.f;
          float zz = acc2[i][j][q] + bcol[j] + hv;
          acc2[i][j][q] = zz;
          s += zz;
        }
        s += __shfl_xor(s, 1, 64); s += __shfl_xor(s, 2, 64);
        s += __shfl_xor(s, 4, 64); s += __shfl_xor(s, 8, 64);
        if ((lane & 15) == 0) part[w * 64 + rl] = s;
      }
    __syncthreads();
    if (tid < 64)
      stat[tid] = (part[tid] + part[64 + tid] + part[128 + tid] + part[192 + tid]) * (1.f / 256.f);
    __syncthreads();
#pragma unroll
    for (int i = 0; i < 4; ++i)
#pragma unroll
      for (int q = 0; q < 4; ++q) {
        int rl = i * 16 + ((lane >> 4) << 2) + q;
        float mu = stat[rl];
        float s2 = 0.f;
#pragma unroll
        for (int j = 0; j < 4; ++j) { float d_ = acc2[i][j][q] - mu; s2 += d_ * d_; }
        s2 += __shfl_xor(s2, 1, 64); s2 += __shfl_xor(s2, 2, 64);
        s2 += __shfl_xor(s2, 4, 64); s2 += __shfl_xor(s2, 8, 64);
        if ((lane & 15) == 0) part[w * 64 + rl] = s2;
      }
    __syncthreads();
    if (tid < 64)
      stat[64 + tid] = 1.f / sqrtf((part[tid] + part[64 + tid] + part[128 + tid] + part[192 + tid]) * (1.f / 256.f) + 1e-5f);
    __syncthreads();
#pragma unroll
    for (int i = 0; i < 4; ++i)
#pragma unroll
      for (int q = 0; q < 4; ++q) {
        int rl = i * 16 + ((lane >> 4) << 2) + q;
        int grow = bm + rl;
        if (grow < M) {
          float mu = stat[rl], rs = stat[64 + rl];
#pragma unroll
          for (int j = 0; j < 4; ++j) {
            int col = w * 64 + j * 16 + (lane & 15);
            float o = (acc2[i][j][q] - mu) * rs * lgc[j] + lbc[j];
            hf[(size_t)grow * 256 + col] = o;
            hb[(size_t)grow * 256 + col] = f2bf(o);
          }
        }
      }
  }
}

// ---------------- CSR gather ----------------
__global__ void gather_pm_dx(const unsigned short* __restrict__ pm, const float* __restrict__ gate,
                             const float* __restrict__ xcur, const int* __restrict__ srcp,
                             const int* __restrict__ rowstart, const int* __restrict__ eids,
                             const float* __restrict__ gb2,
                             unsigned short* __restrict__ pmbf, float* __restrict__ xnxt) {
  int n = blockIdx.x, k = threadIdx.x;
  int s = rowstart[n], e1 = rowstart[n + 1];
  float acc = 0.f, dx = 0.f;
  float b2 = gb2[0];
  float xn = (k < 3) ? xcur[n*3 + k] : 0.f;
  for (int t = s; t < e1; ++t) {
    int e = eids[t];
    acc += bf2f(pm[(size_t)e*HID + k]);
    if (k < 3) dx += (xn - xcur[srcp[e]*3 + k]) * (gate[e] + b2);
  }
  pmbf[(size_t)n*HID + k] = f2bf(acc);
  if (k < 3) xnxt[n*3 + k] = xn + dx;
}

// ---------------- fused readout ----------------
__global__ void readout_kernel(const float* __restrict__ h, const int* __restrict__ gstart,
                               const float* __restrict__ head_W, const float* __restrict__ head_b,
                               float* __restrict__ out) {
  int g = blockIdx.x, k = threadIdx.x;
  int s = gstart[g], e = gstart[g + 1];
  float acc = 0.f;
  for (int n = s; n < e; ++n) acc += h[(size_t)n * HID + k];
  float v = acc * head_W[k];
  __shared__ float red[4];
  int lane = k & 63, wv = k >> 6;
#pragma unroll
  for (int off = 32; off > 0; off >>= 1) v += __shfl_down(v, off, 64);
  if (lane == 0) red[wv] = v;
  __syncthreads();
  if (k == 0) {
    float dot = red[0] + red[1] + red[2] + red[3];
    float c = fmaxf((float)(e - s), 1.0f);
    float val = (dot / c + head_b[0]) * 0.5f;
    out[g] = __fdividef(1.0f, 1.0f + __expf(-val));
  }
}

extern "C" void kernel_launch(void* const* d_in, const int* in_sizes, int n_in,
                              void* d_out, int out_size, void* d_ws, size_t ws_size,
                              hipStream_t stream) {
  (void)in_sizes; (void)n_in; (void)out_size; (void)ws_size;
  const float* a_t      = (const float*)d_in[0];
  const float* c_t      = (const float*)d_in[1];
  const float* e_t      = (const float*)d_in[2];
  const float* x_t      = (const float*)d_in[3];
  const float* g_a      = (const float*)d_in[4];
  const float* g_c      = (const float*)d_in[5];
  const float* g_e      = (const float*)d_in[6];
  const float* atom_W   = (const float*)d_in[7];
  const float* charge_W = (const float*)d_in[8];
  const float* bond_W   = (const float*)d_in[9];
  const float* fuse_W   = (const float*)d_in[10];
  const float* fuse_b   = (const float*)d_in[11];
  const float* lift_W   = (const float*)d_in[12];
  const float* lift_b   = (const float*)d_in[13];
  const float* phim_W1  = (const float*)d_in[14];
  const float* phim_b1  = (const float*)d_in[15];
  const float* phim_W2  = (const float*)d_in[16];
  const float* phim_b2  = (const float*)d_in[17];
  const float* phix_W1  = (const float*)d_in[18];
  const float* phix_b1  = (const float*)d_in[19];
  const float* phix_W2  = (const float*)d_in[20];
  const float* phix_b2  = (const float*)d_in[21];
  const float* psim_W1  = (const float*)d_in[22];
  const float* psim_b1  = (const float*)d_in[23];
  const float* psim_W2  = (const float*)d_in[24];
  const float* psim_b2  = (const float*)d_in[25];
  const float* updh_W1  = (const float*)d_in[26];
  const float* updh_b1  = (const float*)d_in[27];
  const float* updh_W2  = (const float*)d_in[28];
  const float* updh_b2  = (const float*)d_in[29];
  const float* ln_g     = (const float*)d_in[30];
  const float* ln_b     = (const float*)d_in[31];
  const float* head_W   = (const float*)d_in[32];
  const float* head_b   = (const float*)d_in[33];
  const int*   src      = (const int*)d_in[34];
  const int*   dst      = (const int*)d_in[35];
  const int*   ngraph   = (const int*)d_in[36];
  float* out = (float*)d_out;

  char* p = (char*)d_ws;
  auto carve = [&](size_t bytes) -> char* {
    char* r = p; p += (bytes + 255) & ~(size_t)255; return r;
  };
  float*          h     = (float*)carve((size_t)NN*HID*4);
  unsigned short* hbf   = (unsigned short*)carve((size_t)NN*HID*2);
  float*          xposA = (float*)carve((size_t)NN*3*4);
  float*          xposB = (float*)carve((size_t)NN*3*4);
  int*            ie    = (int*)carve((size_t)NE*4);
  float*          tabA  = (float*)carve((size_t)KA*HID*4);
  float*          tabC  = (float*)carve((size_t)KC*HID*4);
  float*          tabEf = (float*)carve((size_t)KE*HID*4);
  float*          gate  = (float*)carve((size_t)NE*4);
  unsigned short* pmbf  = (unsigned short*)carve((size_t)NN*HID*2);
  float*          zbias = (float*)carve(256*4);
  unsigned short* buf01 = (unsigned short*)carve((size_t)2*NE*HID*2);
  unsigned short* bufM  = (unsigned short*)carve((size_t)NE*HID*2);
  unsigned short* bufPM = (unsigned short*)carve((size_t)NE*HID*2);
  unsigned short* P     = (unsigned short*)carve((size_t)4*NN*HID*2);
  int* deg      = (int*)carve(10240*4);
  int* cursor   = (int*)carve(10240*4);
  int* rowstart = (int*)carve(10241*4);
  int* eids     = (int*)carve((size_t)NE*4);
  int* gstart   = (int*)carve((NG+1)*4);
  unsigned short* wNode  = (unsigned short*)carve((size_t)NDEP*1024*256*2);
  unsigned short* wMPM   = (unsigned short*)carve((size_t)NDEP*512*256*2);
  unsigned short* wPhix1 = (unsigned short*)carve((size_t)NDEP*256*256*2);
  unsigned short* wUpd1  = (unsigned short*)carve((size_t)NDEP*256*512*2);
  unsigned short* wUpd2  = (unsigned short*)carve((size_t)NDEP*256*256*2);
  unsigned short* wRbf   = (unsigned short*)carve((size_t)NDEP*16*512*2);
  unsigned int*   wRbfP  = (unsigned int*)carve((size_t)NDEP*8*512*4);
  unsigned short* tabE1  = (unsigned short*)carve((size_t)NDEP*5*512*2);

  unsigned short* c1buf = buf01;
  unsigned short* psbuf = buf01 + (size_t)NE*HID;

  convw_nodeblk<<<dim3(8,4,NDEP), 256, 0, stream>>>(phim_W1, wNode, 0,   0);
  convw_nodeblk<<<dim3(8,4,NDEP), 256, 0, stream>>>(phim_W1, wNode, 256, 256);
  convw_nodeblk<<<dim3(8,4,NDEP), 256, 0, stream>>>(psim_W1, wNode, 0,   512);
  convw_nodeblk<<<dim3(8,4,NDEP), 256, 0, stream>>>(psim_W1, wNode, 256, 768);
  convw_plain<<<dim3(8,4,NDEP), 256, 0, stream>>>(phim_W2, wMPM, 256, 512*256, 0);
  convw_plain<<<dim3(8,4,NDEP), 256, 0, stream>>>(psim_W2, wMPM, 256, 512*256, 256);
  convw_plain<<<dim3(8,4,NDEP), 256, 0, stream>>>(phix_W1, wPhix1, 256, 256*256, 0);
  convw_plain<<<dim3(8,4,NDEP), 256, 0, stream>>>(updh_W2, wUpd2, 256, 256*256, 0);
  convw_plain<<<dim3(16,4,NDEP), 256, 0, stream>>>(updh_W1, wUpd1, 512, 256*512, 0);
  convw_rbf<<<NDEP, 512, 0, stream>>>(phim_W1, psim_W1, wRbf);
  convw_rbf2<<<NDEP, 512, 0, stream>>>(phim_W1, psim_W1, wRbfP);
  hipMemsetAsync(zbias, 0, 256*4, stream);

  tables_kernel<<<KA + KC + KE, 256, 0, stream>>>(atom_W, charge_W, bond_W, fuse_W, fuse_b,
                                                  lift_W, lift_b, tabA, tabC, tabEf);
  tabe1_kernel<<<dim3(5, NDEP), 512, 0, stream>>>(tabEf, phim_W1, phim_b1, psim_W1, psim_b1, tabE1);
  node_init_kernel<<<NN, 256, 0, stream>>>(a_t, c_t, g_a, g_c, x_t, tabA, tabC, h, hbf, xposA);
  edge_init_kernel<<<(NE + 255)/256, 256, 0, stream>>>(e_t, g_e, ie);

  hipMemsetAsync(deg, 0, 10240*4, stream);
  hist_kernel<<<(NE + 255)/256, 256, 0, stream>>>(dst, deg);
  scan_kernel<<<1, 1024, 0, stream>>>(deg, rowstart, cursor);
  fill_kernel<<<(NE + 255)/256, 256, 0, stream>>>(dst, cursor, eids);
  sortrows_kernel<<<(NN + 255)/256, 256, 0, stream>>>(rowstart, eids);
  gbound_kernel<<<(NN + 255)/256, 256, 0, stream>>>(ngraph, gstart);

  dim3 gridP(4, (NN + 63)/64);
  dim3 gridE(1, NE/128);
  dim3 gridE2(1, 2*NE/128);
  dim3 gridNU(1, (NN + 63)/64);

  float* xcur = xposA;
  float* xnxt = xposB;

  for (int d = 0; d < NDEP; ++d) {
    const float* pb2m = phim_b2 + (size_t)d*HID;
    const float* pxb1 = phix_b1 + (size_t)d*HID;
    const float* pxW2 = phix_W2 + (size_t)d*HID;
    const float* pxb2 = phix_b2 + (size_t)d;
    const float* psb2 = psim_b2 + (size_t)d*HID;
    const float* pub1 = updh_b1 + (size_t)d*HID;
    const float* pub2 = updh_b2 + (size_t)d*HID;

    // P = h @ [W1_phim_dst | W1_phim_src | W1_psim_dst | W1_psim_src]
    mfma_gemm<3, false, false, false, true><<<gridP, 256, 0, stream>>>(
        hbf, nullptr, wNode + (size_t)d*1024*256, zbias, nullptr, P, nullptr, NN, 256, 0,
        nullptr, nullptr, nullptr, nullptr, nullptr, nullptr);
    // c1, ps1
    combine2_kernel<<<NE/4, 256, 0, stream>>>(
        src, dst, ie, xcur, P, tabE1 + (size_t)d*5*512, wRbf + (size_t)d*16*512,
        wRbfP + (size_t)d*8*512, c1buf, psbuf);
    // merged m / pm
    mfma_gemm<4, true, false, false, false><<<gridE2, 512, 0, stream>>>(
        buf01, nullptr, wMPM + (size_t)d*512*256, pb2m, psb2, bufM, bufPM, 2*NE, 256, NE,
        nullptr, nullptr, nullptr, nullptr, nullptr, nullptr);
    // gate
    mfma_gemm<0, false, true, false, false><<<gridE, 512, 0, stream>>>(
        bufM, nullptr, wPhix1 + (size_t)d*256*256, pxb1, nullptr, nullptr, nullptr, NE, 256, 0,
        pxW2, gate, nullptr, nullptr, nullptr, nullptr);
    // pm_sum -> pmbf ; x update
    gather_pm_dx<<<NN, 256, 0, stream>>>(bufPM, gate, xcur, src, rowstart, eids, pxb2, pmbf, xnxt);
    // fused upd1 + upd2 + LN
    upd_fused_kernel<<<gridNU, 256, 0, stream>>>(
        hbf, pmbf, wUpd1 + (size_t)d*256*512, wUpd2 + (size_t)d*256*256,
        pub1, pub2, h, hbf, ln_g + (size_t)d*HID, ln_b + (size_t)d*HID, NN);

    float* tmp = xcur; xcur = xnxt; xnxt = tmp;
  }

  readout_kernel<<<NG, 256, 0, stream>>>(h, gstart, head_W, head_b, out);
}